// Round 18
// baseline (346.386 us; speedup 1.0000x reference)
//
#include <hip/hip_runtime.h>
#include <hip/hip_bf16.h>

typedef float f32x2 __attribute__((ext_vector_type(2)));
typedef float f32x4 __attribute__((ext_vector_type(4)));
typedef __bf16 bf16x4 __attribute__((ext_vector_type(4)));
typedef __bf16 bf16x8 __attribute__((ext_vector_type(8)));

__device__ __forceinline__ void gld_lds16(const void* g, void* l) {
  __builtin_amdgcn_global_load_lds((const __attribute__((address_space(1))) void*)g,
                                   (__attribute__((address_space(3))) void*)l, 16, 0, 0);
}

// ---------------------------------------------------------------------------
__global__ void cvt_f32_bf16(const float* __restrict__ in, __bf16* __restrict__ out,
                             int n8) {
  int idx = blockIdx.x * blockDim.x + threadIdx.x;
  if (idx >= n8) return;
  f32x4 a = *(const f32x4*)(in + (size_t)idx * 8);
  f32x4 b = *(const f32x4*)(in + (size_t)idx * 8 + 4);
  bf16x8 o;
#pragma unroll
  for (int j = 0; j < 4; ++j) { o[j] = (__bf16)a[j]; o[4 + j] = (__bf16)b[j]; }
  *(bf16x8*)(out + (size_t)idx * 8) = o;
}

// two-source convert (wk|wv in one launch; contiguous destination)
__global__ void cvt_f32_bf16_2(const float* __restrict__ inA,
                               const float* __restrict__ inB,
                               __bf16* __restrict__ out, int n8half) {
  int idx = blockIdx.x * blockDim.x + threadIdx.x;
  if (idx >= 2 * n8half) return;
  const float* src = (idx < n8half) ? inA + (size_t)idx * 8
                                    : inB + (size_t)(idx - n8half) * 8;
  f32x4 a = *(const f32x4*)src;
  f32x4 b = *(const f32x4*)(src + 4);
  bf16x8 o;
#pragma unroll
  for (int j = 0; j < 4; ++j) { o[j] = (__bf16)a[j]; o[4 + j] = (__bf16)b[j]; }
  *(bf16x8*)(out + (size_t)idx * 8) = o;
}

// ---------------------------------------------------------------------------
// x convert + trig build in one launch.
__global__ void cvt_x_trig(const float* __restrict__ in, __bf16* __restrict__ out,
                           int n8, float* __restrict__ trig, int ntrig) {
  int idx = blockIdx.x * blockDim.x + threadIdx.x;
  if (idx < n8) {
    f32x4 a = *(const f32x4*)(in + (size_t)idx * 8);
    f32x4 b = *(const f32x4*)(in + (size_t)idx * 8 + 4);
    bf16x8 o;
#pragma unroll
    for (int j = 0; j < 4; ++j) { o[j] = (__bf16)a[j]; o[4 + j] = (__bf16)b[j]; }
    *(bf16x8*)(out + (size_t)idx * 8) = o;
  } else if (idx - n8 < ntrig) {
    int t = idx - n8;
    int i = t & 63, s = t >> 6;
    float ang = (float)s * powf(10000.0f, -(float)i * (1.0f / 64.0f));
    float sn, cs;
    sincosf(ang, &sn, &cs);
    trig[t * 2] = cs;
    trig[t * 2 + 1] = sn;
  }
}

// ---------------------------------------------------------------------------
// GEMM  C[M][N] = A[M][K] @ B[N][K]^T, bf16 in, OutT out.  (R7-proven
// 128-class 2-barrier structure.)  KVF=true: fused KV epilogue — K-blocks
// apply RoPE in-register; V-blocks write C transposed into Vt[d][s].
// ---------------------------------------------------------------------------
template <int BM, int BN, typename OutT, bool KVF>
__global__ __launch_bounds__(256) void gemm_bf16(const __bf16* __restrict__ A,
                                                 const __bf16* __restrict__ B0,
                                                 const __bf16* __restrict__ B1,
                                                 int Nsplit, OutT* __restrict__ C,
                                                 int M, int N, int K,
                                                 const float* __restrict__ trig,
                                                 __bf16* __restrict__ Vt) {
  constexpr int MI = BM / 32, NJ = BN / 32;
  constexpr int RA = BM / 32, RB = BN / 32;
  __shared__ __bf16 As[BM * 64] __attribute__((aligned(16)));
  __shared__ __bf16 Bs[BN * 64] __attribute__((aligned(16)));

  const int tid = threadIdx.x;
  const int lane = tid & 63;
  const int w = tid >> 6;
  const int nwg = gridDim.x * gridDim.y;
  const int orig = blockIdx.y * gridDim.x + blockIdx.x;
  const int wgid = (orig & 7) * (nwg >> 3) + (orig >> 3);
  const int m0 = (wgid % gridDim.x) * BM;
  const int n0 = (wgid / gridDim.x) * BN;
  const int li = lane & 15, lg = lane >> 4;

  const __bf16* bsrc[RB];
#pragma unroll
  for (int i = 0; i < RB; ++i) {
    int slot = i * 256 + w * 64 + lane;
    int row = slot >> 3;
    int sch = (slot & 7) ^ (row & 7);
    int n = n0 + row;
    bsrc[i] = (n < Nsplit ? B0 + (size_t)n * K : B1 + (size_t)(n - Nsplit) * K) +
              sch * 8;
  }
  const __bf16* asrc[RA];
#pragma unroll
  for (int i = 0; i < RA; ++i) {
    int slot = i * 256 + w * 64 + lane;
    int row = slot >> 3;
    int sch = (slot & 7) ^ (row & 7);
    asrc[i] = A + (size_t)(m0 + row) * K + sch * 8;
  }

  const int wr = (w >> 1) * (BM / 2);
  const int wc = (w & 1) * (BN / 2);

  f32x4 acc[MI][NJ] = {};

  for (int k0 = 0; k0 < K; k0 += 64) {
    __syncthreads();
#pragma unroll
    for (int i = 0; i < RA; ++i)
      gld_lds16(asrc[i] + k0, &As[(i * 256 + w * 64) * 8]);
#pragma unroll
    for (int i = 0; i < RB; ++i)
      gld_lds16(bsrc[i] + k0, &Bs[(i * 256 + w * 64) * 8]);
    __syncthreads();

#pragma unroll
    for (int u = 0; u < 2; ++u) {
      bf16x8 af[MI], bfr[NJ];
#pragma unroll
      for (int mi = 0; mi < MI; ++mi)
        af[mi] = *(const bf16x8*)&As[(wr + mi * 16 + li) * 64 +
                                     (((u * 4 + lg) ^ (li & 7)) * 8)];
#pragma unroll
      for (int nj = 0; nj < NJ; ++nj)
        bfr[nj] = *(const bf16x8*)&Bs[(wc + nj * 16 + li) * 64 +
                                      (((u * 4 + lg) ^ (li & 7)) * 8)];
#pragma unroll
      for (int mi = 0; mi < MI; ++mi)
#pragma unroll
        for (int nj = 0; nj < NJ; ++nj)
          acc[mi][nj] = __builtin_amdgcn_mfma_f32_16x16x32_bf16(af[mi], bfr[nj],
                                                                acc[mi][nj], 0, 0, 0);
    }
  }

  const int crow = lg * 4;
  if (KVF && n0 >= Nsplit) {
#pragma unroll
    for (int mi = 0; mi < MI; ++mi)
#pragma unroll
      for (int nj = 0; nj < NJ; ++nj) {
        int d = n0 - Nsplit + wc + nj * 16 + li;
        int sb = m0 + wr + mi * 16 + crow;
        bf16x4 pk;
#pragma unroll
        for (int r = 0; r < 4; ++r) pk[r] = (__bf16)acc[mi][nj][r];
        *(bf16x4*)&Vt[(size_t)d * 2048 + sb] = pk;
      }
  } else if (KVF) {
#pragma unroll
    for (int mi = 0; mi < MI; ++mi)
#pragma unroll
      for (int nj = 0; nj < NJ; ++nj) {
        int c = n0 + wc + nj * 16 + li;
        int i = (c & 127) >> 1;
        bool even = (c & 1) == 0;
#pragma unroll
        for (int r = 0; r < 4; ++r) {
          int s = m0 + wr + mi * 16 + crow + r;
          float own = acc[mi][nj][r];
          float oth = __shfl_xor(own, 1);
          f32x2 cs = *(const f32x2*)&trig[((size_t)s * 64 + i) * 2];
          float v = even ? (own * cs[0] - oth * cs[1])
                         : (oth * cs[1] + own * cs[0]);
          C[(size_t)s * N + c] = (OutT)v;
        }
      }
  } else {
#pragma unroll
    for (int mi = 0; mi < MI; ++mi)
#pragma unroll
      for (int nj = 0; nj < NJ; ++nj)
#pragma unroll
        for (int r = 0; r < 4; ++r)
          C[(size_t)(m0 + wr + mi * 16 + crow + r) * N + (n0 + wc + nj * 16 + li)] =
              (OutT)acc[mi][nj][r];
  }
}

// ---------------------------------------------------------------------------
// Causal GQA flash attention v10 = v8f with PREFETCH DEPTH 2.
// 4 LDS buffers (69KB -> still 2 blocks/CU at 138KB).  Per iter: stage tile
// t+2 into buf (t+2)&3 -> vmcnt(8) (waits only tile t's 4 loads; t+1's and
// t+2's 8 stay in flight) -> barrier -> compute buf t&3.  Two iterations of
// load-latency slack (v8 had one).  Buffer safety: writer at t targets
// (t+2)&3 whose last reader was iter t-2 — past barrier(t-1) all waves have
// finished compute(t-2).  Dummy re-stage on tail iters keeps FIFO uniform.
// Everything else identical to v8f (R16).
// ---------------------------------------------------------------------------
__global__ __launch_bounds__(256) void attn_fwd_v10(const __bf16* __restrict__ Q,
                                                    const __bf16* __restrict__ KVb,
                                                    const __bf16* __restrict__ Vt,
                                                    const float* __restrict__ trig,
                                                    __bf16* __restrict__ O,
                                                    const float* __restrict__ wo,
                                                    __bf16* __restrict__ wob) {
  const int tid = threadIdx.x;
  const int lane = tid & 63;
  const int w = tid >> 6;           // 0..3
  const int bid = blockIdx.x;
  const int xcd = bid & 7;
  const int r9 = bid >> 3;          // 0..127
  const int h = xcd * 4 + (r9 & 3);
  const int mb = 31 - (r9 >> 2);    // 31..0, longest blocks first
  const int kvh = h >> 2;           // == xcd
  const int m0 = mb * 64;
  const int rbase = m0 + w * 16;

  __shared__ __bf16 Ks[4][32 * 128] __attribute__((aligned(16)));  // 32 KB
  __shared__ __bf16 Vs[4][128 * 32] __attribute__((aligned(16)));  // 32 KB
  __shared__ __bf16 Ps[4][16 * 40] __attribute__((aligned(16)));   //  5 KB

  const int li = lane & 15, lg = lane >> 4;
  const float qscale = 0.08838834764831845f * 1.4426950408889634f;

  auto stage_k = [&](int k0, int buf) {
#pragma unroll
    for (int i = 0; i < 2; ++i) {
      int slot = i * 256 + tid;
      int row = slot >> 4;                 // 0..31 key
      int sch = (slot & 15) ^ (row & 7);
      gld_lds16(&KVb[(size_t)(k0 + row) * 2048 + kvh * 128 + sch * 8],
                &Ks[buf][(i * 256 + w * 64) * 8]);
    }
  };
  auto stage_v = [&](int k0, int buf) {
#pragma unroll
    for (int i = 0; i < 2; ++i) {
      int slot = i * 256 + tid;
      int row = slot >> 2;                 // 0..127 d
      int sch = (slot & 3) ^ (row & 3);
      gld_lds16(&Vt[(size_t)(kvh * 128 + row) * 2048 + k0 + sch * 8],
                &Vs[buf][(i * 256 + w * 64) * 8]);
    }
  };

  // ---- prologue: Q load + in-register RoPE + scale (lane q-row s=rbase+li)
  const int s = rbase + li;
  bf16x8 qf[4];
  {
    const __bf16* qrow = Q + (size_t)s * 4096 + h * 128;
#pragma unroll
    for (int kc = 0; kc < 4; ++kc) {
      bf16x8 raw = *(const bf16x8*)(qrow + kc * 32 + lg * 8);
#pragma unroll
      for (int jj = 0; jj < 4; ++jj) {
        int i = kc * 16 + lg * 4 + jj;
        f32x2 cs = *(const f32x2*)&trig[((size_t)s * 64 + i) * 2];
        float e = (float)raw[2 * jj], o = (float)raw[2 * jj + 1];
        qf[kc][2 * jj]     = (__bf16)((e * cs[0] - o * cs[1]) * qscale);
        qf[kc][2 * jj + 1] = (__bf16)((e * cs[1] + o * cs[0]) * qscale);
      }
    }
  }

  f32x4 accO[8] = {};
  float plane = 0.f;
  const int ntile = 2 * (mb + 1);   // 32-key tiles through the diagonal block

  // depth-2 prologue: tiles 0 and 1 in flight (8 issues; ntile >= 2 always)
  stage_v(0, 0);
  stage_k(0, 0);
  stage_v(32, 1);
  stage_k(32, 1);

#pragma unroll 1
  for (int t = 0; t < ntile; ++t) {
    const int k0 = t * 32;
    const int cb = t & 3;
    const int nk = (t + 2 < ntile) ? k0 + 64 : k0;   // dummy keeps FIFO uniform
    stage_v(nk, (t + 2) & 3);
    stage_k(nk, (t + 2) & 3);       // 4 issues (tile t+2)

    // tile t's 4 landed (12 outstanding -> leave the newest 8 = t+1, t+2)
    asm volatile("s_waitcnt vmcnt(8)" ::: "memory");
    __builtin_amdgcn_s_barrier();
    __builtin_amdgcn_sched_barrier(0);

    // ---- QK^T swapped: rows=key, cols=q ----
    f32x4 s2[2] = {};
    __builtin_amdgcn_s_setprio(1);
#pragma unroll
    for (int nt = 0; nt < 2; ++nt)
#pragma unroll
      for (int kc = 0; kc < 4; ++kc) {
        bf16x8 kf = *(const bf16x8*)&Ks[cb][(li + 16 * nt) * 128 +
                                           (((4 * kc + lg) ^ (li & 7)) * 8)];
        s2[nt] = __builtin_amdgcn_mfma_f32_16x16x32_bf16(kf, qf[kc], s2[nt], 0, 0, 0);
      }
    __builtin_amdgcn_s_setprio(0);

    // ---- static-max softmax ----
    const bool needmask = (k0 + 31 > rbase);
#pragma unroll
    for (int nt = 0; nt < 2; ++nt) {
      bf16x4 pk;
#pragma unroll
      for (int rr = 0; rr < 4; ++rr) {
        const int key = k0 + 16 * nt + lg * 4 + rr;
        float v = s2[nt][rr];
        if (needmask && key > s) v = -INFINITY;
        float p = exp2f(v);
        plane += p;
        pk[rr] = (__bf16)p;
      }
      *(bf16x4*)&Ps[w][li * 40 + 16 * nt + lg * 4] = pk;
    }
    bf16x8 pa = *(const bf16x8*)&Ps[w][li * 40 + lg * 8];

    // ---- PV (K=32: single A-frag) ----
    __builtin_amdgcn_s_setprio(1);
#pragma unroll
    for (int dt = 0; dt < 8; ++dt) {
      bf16x8 vf = *(const bf16x8*)&Vs[cb][(li + 16 * dt) * 32 +
                                          ((lg ^ (li & 3)) * 8)];
      accO[dt] = __builtin_amdgcn_mfma_f32_16x16x32_bf16(pa, vf, accO[dt], 0, 0, 0);
    }
    __builtin_amdgcn_s_setprio(0);
  }

  // ---- epilogue: reduce plane over lg-duplicates, normalize, store ----
  {
    float sum = plane;
    sum += __shfl_xor(sum, 16);
    sum += __shfl_xor(sum, 32);
    float inv[4];
#pragma unroll
    for (int rr = 0; rr < 4; ++rr) inv[rr] = 1.0f / __shfl(sum, lg * 4 + rr);
#pragma unroll
    for (int dt = 0; dt < 8; ++dt)
#pragma unroll
      for (int rr = 0; rr < 4; ++rr)
        O[(size_t)(rbase + lg * 4 + rr) * 4096 + h * 128 + dt * 16 + li] =
            (__bf16)(accO[dt][rr] * inv[rr]);
  }

  // ---- tail fusion: short blocks (mb <= 23) convert wo (f32->bf16) while
  //      long blocks finish attention.  u in [0,767], bijective. ----
  if (mb <= 23) {
    const int u = (23 - mb) + 24 * ((r9 & 3) + 4 * xcd);
    const int n8 = 4096 * 4096 / 8;
    for (int idx = u * 256 + tid; idx < n8; idx += 768 * 256) {
      f32x4 a = *(const f32x4*)(wo + (size_t)idx * 8);
      f32x4 b = *(const f32x4*)(wo + (size_t)idx * 8 + 4);
      bf16x8 o;
#pragma unroll
      for (int j = 0; j < 4; ++j) { o[j] = (__bf16)a[j]; o[4 + j] = (__bf16)b[j]; }
      *(bf16x8*)(wob + (size_t)idx * 8) = o;
    }
  }
}

// ---------------------------------------------------------------------------
extern "C" void kernel_launch(void* const* d_in, const int* in_sizes, int n_in,
                              void* d_out, int out_size, void* d_ws, size_t ws_size,
                              hipStream_t stream) {
  const float* x  = (const float*)d_in[0];
  const float* wq = (const float*)d_in[1];
  const float* wk = (const float*)d_in[2];
  const float* wv = (const float*)d_in[3];
  const float* wo = (const float*)d_in[4];
  float* out = (float*)d_out;

  const int S = 2048, D = 4096;
  char* ws = (char*)d_ws;
  __bf16* xb  = (__bf16*)ws;                      // 16 MB (reused as AOb)
  __bf16* Qb  = (__bf16*)(ws + 16777216);         // 16 MB
  __bf16* KVb = (__bf16*)(ws + 33554432);         //  8 MB [2048][2048]; K in cols 0..1023
  __bf16* Vt  = (__bf16*)(ws + 41943040);         //  4 MB [1024][2048]
  __bf16* wb  = (__bf16*)(ws + 46137344);         // 32 MB weight scratch
  float*  trig = (float*)(ws + 79691776);         //  1 MB
  __bf16* AOb = xb;

  // x -> bf16 + trig table, one launch
  cvt_x_trig<<<(S * D / 8 + 2048 * 64 + 255) / 256, 256, 0, stream>>>(
      x, xb, S * D / 8, trig, 2048 * 64);

  cvt_f32_bf16<<<(D * D / 8 + 255) / 256, 256, 0, stream>>>(wq, wb, D * D / 8);
  gemm_bf16<128, 128, __bf16, false><<<dim3(16, 32), 256, 0, stream>>>(
      xb, wb, wb, 1 << 30, Qb, S, D, D, nullptr, nullptr);

  // wk|wv -> bf16 in a single launch
  cvt_f32_bf16_2<<<(2 * 1024 * D / 8 + 255) / 256, 256, 0, stream>>>(
      wk, wv, wb, 1024 * D / 8);
  // KV projection with fused epilogue: K-RoPE in-register, V written transposed.
  gemm_bf16<64, 128, __bf16, true><<<dim3(32, 16), 256, 0, stream>>>(
      xb, wb, wb + (size_t)1024 * D, 1024, KVb, S, 2048, D, trig, Vt);

  // attention (depth-2 prefetch) + tail-fused wo convert
  attn_fwd_v10<<<1024, 256, 0, stream>>>(Qb, KVb, Vt, trig, AOb, wo, wb);

  gemm_bf16<128, 128, float, false><<<dim3(16, 32), 256, 0, stream>>>(
      AOb, wb, wb, 1 << 30, out, S, D, D, nullptr, nullptr);
}

// Round 19
// 341.162 us; speedup vs baseline: 1.0153x; 1.0153x over previous
//
#include <hip/hip_runtime.h>
#include <hip/hip_bf16.h>

typedef float f32x2 __attribute__((ext_vector_type(2)));
typedef float f32x4 __attribute__((ext_vector_type(4)));
typedef __bf16 bf16x4 __attribute__((ext_vector_type(4)));
typedef __bf16 bf16x8 __attribute__((ext_vector_type(8)));

__device__ __forceinline__ void gld_lds16(const void* g, void* l) {
  __builtin_amdgcn_global_load_lds((const __attribute__((address_space(1))) void*)g,
                                   (__attribute__((address_space(3))) void*)l, 16, 0, 0);
}

// ---------------------------------------------------------------------------
__global__ void cvt_f32_bf16(const float* __restrict__ in, __bf16* __restrict__ out,
                             int n8) {
  int idx = blockIdx.x * blockDim.x + threadIdx.x;
  if (idx >= n8) return;
  f32x4 a = *(const f32x4*)(in + (size_t)idx * 8);
  f32x4 b = *(const f32x4*)(in + (size_t)idx * 8 + 4);
  bf16x8 o;
#pragma unroll
  for (int j = 0; j < 4; ++j) { o[j] = (__bf16)a[j]; o[4 + j] = (__bf16)b[j]; }
  *(bf16x8*)(out + (size_t)idx * 8) = o;
}

// two-source convert (wk|wv in one launch; contiguous destination)
__global__ void cvt_f32_bf16_2(const float* __restrict__ inA,
                               const float* __restrict__ inB,
                               __bf16* __restrict__ out, int n8half) {
  int idx = blockIdx.x * blockDim.x + threadIdx.x;
  if (idx >= 2 * n8half) return;
  const float* src = (idx < n8half) ? inA + (size_t)idx * 8
                                    : inB + (size_t)(idx - n8half) * 8;
  f32x4 a = *(const f32x4*)src;
  f32x4 b = *(const f32x4*)(src + 4);
  bf16x8 o;
#pragma unroll
  for (int j = 0; j < 4; ++j) { o[j] = (__bf16)a[j]; o[4 + j] = (__bf16)b[j]; }
  *(bf16x8*)(out + (size_t)idx * 8) = o;
}

// ---------------------------------------------------------------------------
// x convert + trig build in one launch.
__global__ void cvt_x_trig(const float* __restrict__ in, __bf16* __restrict__ out,
                           int n8, float* __restrict__ trig, int ntrig) {
  int idx = blockIdx.x * blockDim.x + threadIdx.x;
  if (idx < n8) {
    f32x4 a = *(const f32x4*)(in + (size_t)idx * 8);
    f32x4 b = *(const f32x4*)(in + (size_t)idx * 8 + 4);
    bf16x8 o;
#pragma unroll
    for (int j = 0; j < 4; ++j) { o[j] = (__bf16)a[j]; o[4 + j] = (__bf16)b[j]; }
    *(bf16x8*)(out + (size_t)idx * 8) = o;
  } else if (idx - n8 < ntrig) {
    int t = idx - n8;
    int i = t & 63, s = t >> 6;
    float ang = (float)s * powf(10000.0f, -(float)i * (1.0f / 64.0f));
    float sn, cs;
    sincosf(ang, &sn, &cs);
    trig[t * 2] = cs;
    trig[t * 2 + 1] = sn;
  }
}

// ---------------------------------------------------------------------------
// GEMM  C[M][N] = A[M][K] @ B[N][K]^T, bf16 in, OutT out.  (R7-proven
// 128-class 2-barrier structure.)  KVF=true: fused KV epilogue — K-blocks
// apply RoPE in-register; V-blocks write C transposed into Vt[d][s].
// ---------------------------------------------------------------------------
template <int BM, int BN, typename OutT, bool KVF>
__global__ __launch_bounds__(256) void gemm_bf16(const __bf16* __restrict__ A,
                                                 const __bf16* __restrict__ B0,
                                                 const __bf16* __restrict__ B1,
                                                 int Nsplit, OutT* __restrict__ C,
                                                 int M, int N, int K,
                                                 const float* __restrict__ trig,
                                                 __bf16* __restrict__ Vt) {
  constexpr int MI = BM / 32, NJ = BN / 32;
  constexpr int RA = BM / 32, RB = BN / 32;
  __shared__ __bf16 As[BM * 64] __attribute__((aligned(16)));
  __shared__ __bf16 Bs[BN * 64] __attribute__((aligned(16)));

  const int tid = threadIdx.x;
  const int lane = tid & 63;
  const int w = tid >> 6;
  const int nwg = gridDim.x * gridDim.y;
  const int orig = blockIdx.y * gridDim.x + blockIdx.x;
  const int wgid = (orig & 7) * (nwg >> 3) + (orig >> 3);
  const int m0 = (wgid % gridDim.x) * BM;
  const int n0 = (wgid / gridDim.x) * BN;
  const int li = lane & 15, lg = lane >> 4;

  const __bf16* bsrc[RB];
#pragma unroll
  for (int i = 0; i < RB; ++i) {
    int slot = i * 256 + w * 64 + lane;
    int row = slot >> 3;
    int sch = (slot & 7) ^ (row & 7);
    int n = n0 + row;
    bsrc[i] = (n < Nsplit ? B0 + (size_t)n * K : B1 + (size_t)(n - Nsplit) * K) +
              sch * 8;
  }
  const __bf16* asrc[RA];
#pragma unroll
  for (int i = 0; i < RA; ++i) {
    int slot = i * 256 + w * 64 + lane;
    int row = slot >> 3;
    int sch = (slot & 7) ^ (row & 7);
    asrc[i] = A + (size_t)(m0 + row) * K + sch * 8;
  }

  const int wr = (w >> 1) * (BM / 2);
  const int wc = (w & 1) * (BN / 2);

  f32x4 acc[MI][NJ] = {};

  for (int k0 = 0; k0 < K; k0 += 64) {
    __syncthreads();
#pragma unroll
    for (int i = 0; i < RA; ++i)
      gld_lds16(asrc[i] + k0, &As[(i * 256 + w * 64) * 8]);
#pragma unroll
    for (int i = 0; i < RB; ++i)
      gld_lds16(bsrc[i] + k0, &Bs[(i * 256 + w * 64) * 8]);
    __syncthreads();

#pragma unroll
    for (int u = 0; u < 2; ++u) {
      bf16x8 af[MI], bfr[NJ];
#pragma unroll
      for (int mi = 0; mi < MI; ++mi)
        af[mi] = *(const bf16x8*)&As[(wr + mi * 16 + li) * 64 +
                                     (((u * 4 + lg) ^ (li & 7)) * 8)];
#pragma unroll
      for (int nj = 0; nj < NJ; ++nj)
        bfr[nj] = *(const bf16x8*)&Bs[(wc + nj * 16 + li) * 64 +
                                      (((u * 4 + lg) ^ (li & 7)) * 8)];
#pragma unroll
      for (int mi = 0; mi < MI; ++mi)
#pragma unroll
        for (int nj = 0; nj < NJ; ++nj)
          acc[mi][nj] = __builtin_amdgcn_mfma_f32_16x16x32_bf16(af[mi], bfr[nj],
                                                                acc[mi][nj], 0, 0, 0);
    }
  }

  const int crow = lg * 4;
  if (KVF && n0 >= Nsplit) {
#pragma unroll
    for (int mi = 0; mi < MI; ++mi)
#pragma unroll
      for (int nj = 0; nj < NJ; ++nj) {
        int d = n0 - Nsplit + wc + nj * 16 + li;
        int sb = m0 + wr + mi * 16 + crow;
        bf16x4 pk;
#pragma unroll
        for (int r = 0; r < 4; ++r) pk[r] = (__bf16)acc[mi][nj][r];
        *(bf16x4*)&Vt[(size_t)d * 2048 + sb] = pk;
      }
  } else if (KVF) {
#pragma unroll
    for (int mi = 0; mi < MI; ++mi)
#pragma unroll
      for (int nj = 0; nj < NJ; ++nj) {
        int c = n0 + wc + nj * 16 + li;
        int i = (c & 127) >> 1;
        bool even = (c & 1) == 0;
#pragma unroll
        for (int r = 0; r < 4; ++r) {
          int s = m0 + wr + mi * 16 + crow + r;
          float own = acc[mi][nj][r];
          float oth = __shfl_xor(own, 1);
          f32x2 cs = *(const f32x2*)&trig[((size_t)s * 64 + i) * 2];
          float v = even ? (own * cs[0] - oth * cs[1])
                         : (oth * cs[1] + own * cs[0]);
          C[(size_t)s * N + c] = (OutT)v;
        }
      }
  } else {
#pragma unroll
    for (int mi = 0; mi < MI; ++mi)
#pragma unroll
      for (int nj = 0; nj < NJ; ++nj)
#pragma unroll
        for (int r = 0; r < 4; ++r)
          C[(size_t)(m0 + wr + mi * 16 + crow + r) * N + (n0 + wc + nj * 16 + li)] =
              (OutT)acc[mi][nj][r];
  }
}

// ---------------------------------------------------------------------------
// Causal GQA flash attention v11 = v8f (R16, depth-1) with three VALU/LDS
// surgical fixes:
//  (1) V swizzle g(row)=(row>>1)&3 both sides (was row&3: only 2 distinct
//      chunk slots per bank-parity class -> 4-way conflict; now 4 slots ->
//      2-way = free).  Read-side XOR ((li>>1)&3) is dt-independent.
//  (2) wave-uniform needmask branch: clean path (all tiles except the 1-2
//      diagonal ones per wave) skips 16 cmp+cndmask per tile.
//  (3) plane -> pl[4] partial accumulators (f32 add chain depth 8 -> 2).
// ---------------------------------------------------------------------------
__global__ __launch_bounds__(256) void attn_fwd_v11(const __bf16* __restrict__ Q,
                                                    const __bf16* __restrict__ KVb,
                                                    const __bf16* __restrict__ Vt,
                                                    const float* __restrict__ trig,
                                                    __bf16* __restrict__ O,
                                                    const float* __restrict__ wo,
                                                    __bf16* __restrict__ wob) {
  const int tid = threadIdx.x;
  const int lane = tid & 63;
  const int w = tid >> 6;           // 0..3
  const int bid = blockIdx.x;
  const int xcd = bid & 7;
  const int r9 = bid >> 3;          // 0..127
  const int h = xcd * 4 + (r9 & 3);
  const int mb = 31 - (r9 >> 2);    // 31..0, longest blocks first
  const int kvh = h >> 2;           // == xcd
  const int m0 = mb * 64;
  const int rbase = m0 + w * 16;

  __shared__ __bf16 Ks[3][32 * 128] __attribute__((aligned(16)));  // 24 KB
  __shared__ __bf16 Vs[3][128 * 32] __attribute__((aligned(16)));  // 24 KB
  __shared__ __bf16 Ps[4][16 * 40] __attribute__((aligned(16)));   //  5 KB

  const int li = lane & 15, lg = lane >> 4;
  const float qscale = 0.08838834764831845f * 1.4426950408889634f;

  auto stage_k = [&](int k0, int buf) {
#pragma unroll
    for (int i = 0; i < 2; ++i) {
      int slot = i * 256 + tid;
      int row = slot >> 4;                 // 0..31 key
      int sch = (slot & 15) ^ (row & 7);
      gld_lds16(&KVb[(size_t)(k0 + row) * 2048 + kvh * 128 + sch * 8],
                &Ks[buf][(i * 256 + w * 64) * 8]);
    }
  };
  auto stage_v = [&](int k0, int buf) {
#pragma unroll
    for (int i = 0; i < 2; ++i) {
      int slot = i * 256 + tid;
      int row = slot >> 2;                 // 0..127 d
      int sch = (slot & 3) ^ ((row >> 1) & 3);   // (1) new involution
      gld_lds16(&Vt[(size_t)(kvh * 128 + row) * 2048 + k0 + sch * 8],
                &Vs[buf][(i * 256 + w * 64) * 8]);
    }
  };

  // ---- prologue: Q load + in-register RoPE + scale (lane q-row s=rbase+li)
  const int s = rbase + li;
  bf16x8 qf[4];
  {
    const __bf16* qrow = Q + (size_t)s * 4096 + h * 128;
#pragma unroll
    for (int kc = 0; kc < 4; ++kc) {
      bf16x8 raw = *(const bf16x8*)(qrow + kc * 32 + lg * 8);
#pragma unroll
      for (int jj = 0; jj < 4; ++jj) {
        int i = kc * 16 + lg * 4 + jj;
        f32x2 cs = *(const f32x2*)&trig[((size_t)s * 64 + i) * 2];
        float e = (float)raw[2 * jj], o = (float)raw[2 * jj + 1];
        qf[kc][2 * jj]     = (__bf16)((e * cs[0] - o * cs[1]) * qscale);
        qf[kc][2 * jj + 1] = (__bf16)((e * cs[1] + o * cs[0]) * qscale);
      }
    }
  }

  f32x4 accO[8] = {};
  float pl[4] = {0.f, 0.f, 0.f, 0.f};   // (3) partial row-sum accumulators
  const int ntile = 2 * (mb + 1);       // 32-key tiles through the diagonal

  stage_v(0, 0);
  stage_k(0, 0);                        // 4 issues (tile 0)

#pragma unroll 1
  for (int t = 0; t < ntile; ++t) {
    const int k0 = t * 32;
    const int cb = t % 3;
    const int nk = (t + 1 < ntile) ? k0 + 32 : k0;   // dummy keeps FIFO uniform
    stage_v(nk, (t + 1) % 3);
    stage_k(nk, (t + 1) % 3);           // 4 issues (tile t+1)

    // tile t's 4 landed (8 outstanding -> leave the newest 4)
    asm volatile("s_waitcnt vmcnt(4)" ::: "memory");
    __builtin_amdgcn_s_barrier();
    __builtin_amdgcn_sched_barrier(0);

    // ---- QK^T swapped: rows=key, cols=q ----
    f32x4 s2[2] = {};
    __builtin_amdgcn_s_setprio(1);
#pragma unroll
    for (int nt = 0; nt < 2; ++nt)
#pragma unroll
      for (int kc = 0; kc < 4; ++kc) {
        bf16x8 kf = *(const bf16x8*)&Ks[cb][(li + 16 * nt) * 128 +
                                           (((4 * kc + lg) ^ (li & 7)) * 8)];
        s2[nt] = __builtin_amdgcn_mfma_f32_16x16x32_bf16(kf, qf[kc], s2[nt], 0, 0, 0);
      }
    __builtin_amdgcn_s_setprio(0);

    // ---- static-max softmax; (2) wave-uniform mask branch ----
    if (k0 + 31 > rbase) {              // diagonal tiles only
#pragma unroll
      for (int nt = 0; nt < 2; ++nt) {
        bf16x4 pk;
#pragma unroll
        for (int rr = 0; rr < 4; ++rr) {
          const int key = k0 + 16 * nt + lg * 4 + rr;
          float v = s2[nt][rr];
          if (key > s) v = -INFINITY;
          float p = exp2f(v);
          pl[rr] += p;
          pk[rr] = (__bf16)p;
        }
        *(bf16x4*)&Ps[w][li * 40 + 16 * nt + lg * 4] = pk;
      }
    } else {                            // clean path: no compares
#pragma unroll
      for (int nt = 0; nt < 2; ++nt) {
        bf16x4 pk;
#pragma unroll
        for (int rr = 0; rr < 4; ++rr) {
          float p = exp2f(s2[nt][rr]);
          pl[rr] += p;
          pk[rr] = (__bf16)p;
        }
        *(bf16x4*)&Ps[w][li * 40 + 16 * nt + lg * 4] = pk;
      }
    }
    bf16x8 pa = *(const bf16x8*)&Ps[w][li * 40 + lg * 8];

    // ---- PV (K=32: single A-frag); (1) fixed V-read swizzle ----
    __builtin_amdgcn_s_setprio(1);
#pragma unroll
    for (int dt = 0; dt < 8; ++dt) {
      bf16x8 vf = *(const bf16x8*)&Vs[cb][(li + 16 * dt) * 32 +
                                          ((lg ^ ((li >> 1) & 3)) * 8)];
      accO[dt] = __builtin_amdgcn_mfma_f32_16x16x32_bf16(pa, vf, accO[dt], 0, 0, 0);
    }
    __builtin_amdgcn_s_setprio(0);
  }

  // ---- epilogue: combine partials, reduce over lg-duplicates, store ----
  {
    float sum = (pl[0] + pl[1]) + (pl[2] + pl[3]);
    sum += __shfl_xor(sum, 16);
    sum += __shfl_xor(sum, 32);
    float inv[4];
#pragma unroll
    for (int rr = 0; rr < 4; ++rr) inv[rr] = 1.0f / __shfl(sum, lg * 4 + rr);
#pragma unroll
    for (int dt = 0; dt < 8; ++dt)
#pragma unroll
      for (int rr = 0; rr < 4; ++rr)
        O[(size_t)(rbase + lg * 4 + rr) * 4096 + h * 128 + dt * 16 + li] =
            (__bf16)(accO[dt][rr] * inv[rr]);
  }

  // ---- tail fusion: short blocks (mb <= 23) convert wo (f32->bf16) ----
  if (mb <= 23) {
    const int u = (23 - mb) + 24 * ((r9 & 3) + 4 * xcd);  // 0..767 unique
    const int n8 = 4096 * 4096 / 8;
    for (int idx = u * 256 + tid; idx < n8; idx += 768 * 256) {
      f32x4 a = *(const f32x4*)(wo + (size_t)idx * 8);
      f32x4 b = *(const f32x4*)(wo + (size_t)idx * 8 + 4);
      bf16x8 o;
#pragma unroll
      for (int j = 0; j < 4; ++j) { o[j] = (__bf16)a[j]; o[4 + j] = (__bf16)b[j]; }
      *(bf16x8*)(wob + (size_t)idx * 8) = o;
    }
  }
}

// ---------------------------------------------------------------------------
extern "C" void kernel_launch(void* const* d_in, const int* in_sizes, int n_in,
                              void* d_out, int out_size, void* d_ws, size_t ws_size,
                              hipStream_t stream) {
  const float* x  = (const float*)d_in[0];
  const float* wq = (const float*)d_in[1];
  const float* wk = (const float*)d_in[2];
  const float* wv = (const float*)d_in[3];
  const float* wo = (const float*)d_in[4];
  float* out = (float*)d_out;

  const int S = 2048, D = 4096;
  char* ws = (char*)d_ws;
  __bf16* xb  = (__bf16*)ws;                      // 16 MB (reused as AOb)
  __bf16* Qb  = (__bf16*)(ws + 16777216);         // 16 MB
  __bf16* KVb = (__bf16*)(ws + 33554432);         //  8 MB [2048][2048]; K in cols 0..1023
  __bf16* Vt  = (__bf16*)(ws + 41943040);         //  4 MB [1024][2048]
  __bf16* wb  = (__bf16*)(ws + 46137344);         // 32 MB weight scratch
  float*  trig = (float*)(ws + 79691776);         //  1 MB
  __bf16* AOb = xb;

  // x -> bf16 + trig table, one launch
  cvt_x_trig<<<(S * D / 8 + 2048 * 64 + 255) / 256, 256, 0, stream>>>(
      x, xb, S * D / 8, trig, 2048 * 64);

  cvt_f32_bf16<<<(D * D / 8 + 255) / 256, 256, 0, stream>>>(wq, wb, D * D / 8);
  gemm_bf16<128, 128, __bf16, false><<<dim3(16, 32), 256, 0, stream>>>(
      xb, wb, wb, 1 << 30, Qb, S, D, D, nullptr, nullptr);

  // wk|wv -> bf16 in a single launch
  cvt_f32_bf16_2<<<(2 * 1024 * D / 8 + 255) / 256, 256, 0, stream>>>(
      wk, wv, wb, 1024 * D / 8);
  // KV projection with fused epilogue: K-RoPE in-register, V written transposed.
  gemm_bf16<64, 128, __bf16, true><<<dim3(32, 16), 256, 0, stream>>>(
      xb, wb, wb + (size_t)1024 * D, 1024, KVb, S, 2048, D, trig, Vt);

  // attention + tail-fused wo convert
  attn_fwd_v11<<<1024, 256, 0, stream>>>(Qb, KVb, Vt, trig, AOb, wo, wb);

  gemm_bf16<128, 128, float, false><<<dim3(16, 32), 256, 0, stream>>>(
      AOb, wb, wb, 1 << 30, out, S, D, D, nullptr, nullptr);
}